// Round 9
// baseline (690.349 us; speedup 1.0000x reference)
//
#include <hip/hip_runtime.h>
#include <hip/hip_bf16.h>
#include <math.h>

#define NPRED 65536
#define NGT   128
#define NCLS  256
#define CAP   12288
#define VCAP  160
#define VSLOT 129    // costV inner stride: >=128 slots, 129 for conflict-free column writes
#define NLIST 129    // per-row sorted prefix: 128 (max |V|) + 1 guarantees a fresh head
#define LSTRIDE 132
#define KEEP  2048
#define KMIN  1418
#define GSPLIT 4     // k_cost g-split: 4 blocks of 32 gts per 256-pred slab
#define GPB   (NGT / GSPLIT)
#define SENT_I 0x7FFFFFFF

// ---------- numeric helpers (match reference op order; no FMA contraction) ----------

// monotone map f32 -> uint32 (order-preserving for all floats)
__device__ __forceinline__ unsigned f2u(float f) {
    unsigned u = __float_as_uint(f);
    return (u & 0x80000000u) ? ~u : (u | 0x80000000u);
}
__device__ __forceinline__ float u2f(unsigned x) {
    unsigned u = (x & 0x80000000u) ? (x ^ 0x80000000u) : ~x;
    return __uint_as_float(u);
}
// monotone map f64 -> uint64 (order-preserving; used for packed LSA reduction)
__device__ __forceinline__ unsigned long long d2u(double d) {
    unsigned long long u = (unsigned long long)__double_as_longlong(d);
    return (u & 0x8000000000000000ull) ? ~u : (u | 0x8000000000000000ull);
}
__device__ __forceinline__ double u2d(unsigned long long x) {
    unsigned long long u = (x & 0x8000000000000000ull) ? (x ^ 0x8000000000000000ull) : ~x;
    return __longlong_as_double((long long)u);
}

__device__ __forceinline__ float giou3d(
    float pl0, float pl1, float pl2, float ph0, float ph1, float ph2, float pvol,
    float gl0, float gl1, float gl2, float gh0, float gh1, float gh2, float gvol)
{
#pragma clang fp contract(off)
    float c0 = fmaxf(fminf(ph0, gh0) - fmaxf(pl0, gl0), 0.0f);
    float c1 = fmaxf(fminf(ph1, gh1) - fmaxf(pl1, gl1), 0.0f);
    float c2 = fmaxf(fminf(ph2, gh2) - fmaxf(pl2, gl2), 0.0f);
    float overlap = (c0 * c1) * c2;
    float uni = fmaxf((pvol + gvol) - overlap, 1e-6f);
    float iou = overlap / uni;
    float e0 = fmaxf(fmaxf(ph0, gh0) - fminf(pl0, gl0), 0.0f);
    float e1 = fmaxf(fmaxf(ph1, gh1) - fminf(pl1, gl1), 0.0f);
    float e2 = fmaxf(fmaxf(ph2, gh2) - fminf(pl2, gl2), 0.0f);
    float enc = fmaxf((e0 * e1) * e2, 1e-6f);
    return iou - (enc - uni) / enc;
}

// ---------- kernels ----------

// coalesced cls load + LDS transpose + sigmoid: costT[g][p] = -sigmoid(cls[p][lab[g]])
// block 0 also performs the (former k_init) counter zeroing - no later-kernel hazard.
__global__ __launch_bounds__(256) void k_gather(
    const float* __restrict__ cls, const int* __restrict__ lab,
    float* __restrict__ costT,
    int* __restrict__ ccnt, unsigned* __restrict__ cmax, int* __restrict__ failFlag)
{
#pragma clang fp contract(off)
    __shared__ float tile[64][NCLS + 1];
    __shared__ int labl[NGT];
    int tid = threadIdx.x;
    int p0 = blockIdx.x * 64;
    if (blockIdx.x == 0) {
        if (tid < NGT) { ccnt[tid] = 0; cmax[tid] = 0u; }
        if (tid == 0) *failFlag = 0;
    }
    if (tid < NGT) labl[tid] = lab[tid];
    for (int it = 0; it < 16; ++it) {
        int row = it * 4 + (tid >> 6);
        int col = (tid & 63) * 4;
        const float4 v = *(const float4*)&cls[(size_t)(p0 + row) * NCLS + col];
        tile[row][col + 0] = v.x; tile[row][col + 1] = v.y;
        tile[row][col + 2] = v.z; tile[row][col + 3] = v.w;
    }
    __syncthreads();
    int lane = tid & 63;
    for (int rep = 0; rep < 32; ++rep) {
        int g = rep * 4 + (tid >> 6);
        float val = tile[lane][labl[g]];
        double s = 1.0 / (1.0 + exp(-(double)val));
        costT[(size_t)g * NPRED + p0 + lane] = -(float)s;
    }
}

// two-pass, block-aggregated atomics. Grid: (NPRED/256)*GSPLIT blocks x 256 thr.
// Block handles 256 preds x GPB gts. Pass A: giou + LDS max/count + costT RMW;
// per-thread giou kept in registers (gior) so Pass B skips the recompute.
__global__ __launch_bounds__(256) void k_cost(
    const float* __restrict__ pc, const float* __restrict__ ps,
    const float* __restrict__ gc, const float* __restrict__ gs,
    float* __restrict__ costT, int* __restrict__ ccnt, unsigned* __restrict__ cmax,
    int2* __restrict__ cpair)
{
#pragma clang fp contract(off)
    __shared__ float gb[GPB][6];
    __shared__ float gvol[GPB];
    __shared__ unsigned smax[GPB];
    __shared__ int cntl[GPB], basel[GPB], curl[GPB];
    int tid = threadIdx.x;
    int lane = tid & 63;
    int g0 = (blockIdx.x & (GSPLIT - 1)) * GPB;
    int p  = (blockIdx.x >> 2) * 256 + tid;

    if (tid < GPB) {
        int g = g0 + tid;
        float c0 = gc[g * 3 + 0], c1 = gc[g * 3 + 1], c2 = gc[g * 3 + 2];
        float s0 = gs[g * 3 + 0], s1 = gs[g * 3 + 1], s2 = gs[g * 3 + 2];
        float l0 = c0 - s0 / 2.0f, l1 = c1 - s1 / 2.0f, l2 = c2 - s2 / 2.0f;
        float h0 = c0 + s0 / 2.0f, h1 = c1 + s1 / 2.0f, h2 = c2 + s2 / 2.0f;
        gb[tid][0] = l0; gb[tid][1] = l1; gb[tid][2] = l2;
        gb[tid][3] = h0; gb[tid][4] = h1; gb[tid][5] = h2;
        gvol[tid] = ((h0 - l0) * (h1 - l1)) * (h2 - l2);
        smax[tid] = 0u; cntl[tid] = 0; curl[tid] = 0;
    }
    __syncthreads();

    float c0 = pc[p * 3 + 0], c1 = pc[p * 3 + 1], c2 = pc[p * 3 + 2];
    float s0 = ps[p * 3 + 0], s1 = ps[p * 3 + 1], s2 = ps[p * 3 + 2];
    float pl0 = c0 - s0 / 2.0f, pl1 = c1 - s1 / 2.0f, pl2 = c2 - s2 / 2.0f;
    float ph0 = c0 + s0 / 2.0f, ph1 = c1 + s1 / 2.0f, ph2 = c2 + s2 / 2.0f;
    float pvol = ((ph0 - pl0) * (ph1 - pl1)) * (ph2 - pl2);

    float gior[GPB];   // fully-unrolled static indexing -> stays in VGPRs

    // Pass A: no blocking global atomics in the loop
#pragma unroll
    for (int gg = 0; gg < GPB; ++gg) {
        float gio = giou3d(pl0, pl1, pl2, ph0, ph1, ph2, pvol,
                           gb[gg][0], gb[gg][1], gb[gg][2], gb[gg][3], gb[gg][4], gb[gg][5],
                           gvol[gg]);
        gior[gg] = gio;
        float m = gio;
        for (int off = 32; off; off >>= 1) m = fmaxf(m, __shfl_xor(m, off, 64));
        unsigned long long mask = __ballot(gio > 0.25f);
        if (lane == 0) {
            atomicMax(&smax[gg], f2u(m));
            atomicAdd(&cntl[gg], __popcll(mask));
        }
        size_t ij = (size_t)(g0 + gg) * NPRED + p;
        float ns = costT[ij];                 // staged -sigmoid
        costT[ij] = ns + (2.0f * (-gio));     // == (-sg) + (2.0f*(-gio))
    }
    __syncthreads();
    // one parallel global atomic per gt (32 concurrent RTs); cmax fire-and-forget
    if (tid < GPB) {
        atomicMax(&cmax[g0 + tid], smax[tid]);
        basel[tid] = atomicAdd(&ccnt[g0 + tid], cntl[tid]);
    }
    __syncthreads();

    // Pass B: scatter candidates from register-cached giou (bit-identical values)
#pragma unroll
    for (int gg = 0; gg < GPB; ++gg) {
        float gio = gior[gg];
        bool cand = (gio > 0.25f);
        unsigned long long mask = __ballot(cand);
        int cnt = __popcll(mask);
        int wo = 0;
        if (lane == 0 && cnt) wo = atomicAdd(&curl[gg], cnt);
        wo = __shfl(wo, 0, 64);
        if (cand) {
            int slot = basel[gg] + wo + __popcll(mask & ((1ull << lane) - 1ull));
            if (slot < CAP)
                cpair[(size_t)(g0 + gg) * CAP + slot] = make_int2(p, __float_as_int(gio));
        }
    }
}

// per-row exact top-NLIST smallest (value, col), sorted ascending by (val, col).
// Fast path: per-thread register top-8 over a single coalesced float4 scan,
// 2048-candidate bitonic sort in LDS, provable-exactness check. On the
// (astronomically rare) check failure, falls to the exact radix-select.
// Block NGT (the +1 block) performs the former k_sort rank-sort of cmax.
__global__ __launch_bounds__(256) void k_toprow(
    const float* __restrict__ costT, int2* __restrict__ rowlist,
    const unsigned* __restrict__ cmax, int* __restrict__ order)
{
    __shared__ unsigned long long keys[2048];
    __shared__ int hist[256];
    __shared__ unsigned long long sh_prefix;
    __shared__ int sh_rank, sh_cnt, sh_ok;
    __shared__ unsigned msort[NGT];
    int tid = threadIdx.x;
    int row = blockIdx.x;

    if (row == NGT) {   // fused k_sort (independent of toprow work)
        if (tid < NGT) msort[tid] = cmax[tid];
        __syncthreads();
        if (tid < NGT) {
            unsigned mt = msort[tid];
            int r = 0;
            for (int k = 0; k < NGT; ++k) {
                unsigned mk = msort[k];
                if (mk < mt || (mk == mt && k < tid)) r++;
            }
            order[r] = tid;
        }
        return;
    }
    const float* crow = costT + (size_t)row * NPRED;

    // ---- fast path: per-thread top-8 (sorted ascending in registers) ----
    unsigned long long lv[8];
#pragma unroll
    for (int q = 0; q < 8; ++q) lv[q] = ~0ull;
    const float4* crow4 = (const float4*)crow;
    for (int it = tid; it < NPRED / 4; it += 256) {
        float4 v4 = crow4[it];
        int j = it * 4;
        float vv[4] = {v4.x, v4.y, v4.z, v4.w};
#pragma unroll
        for (int e = 0; e < 4; ++e) {
            unsigned long long key =
                ((unsigned long long)f2u(vv[e]) << 32) | (unsigned)(j + e);
            if (key < lv[7]) {
                unsigned long long c = key;
#pragma unroll
                for (int q = 0; q < 8; ++q) {
                    unsigned long long mx = (c > lv[q]) ? c : lv[q];
                    unsigned long long mn = (c > lv[q]) ? lv[q] : c;
                    lv[q] = mn; c = mx;
                }
            }
        }
    }
#pragma unroll
    for (int q = 0; q < 8; ++q) keys[tid * 8 + q] = lv[q];
    if (tid == 0) sh_ok = 1;
    __syncthreads();

    // bitonic sort 2048 candidate keys ascending
    for (int k = 2; k <= 2048; k <<= 1) {
        for (int j2 = k >> 1; j2 > 0; j2 >>= 1) {
            for (int i = tid; i < 2048; i += 256) {
                int ixj = i ^ j2;
                if (ixj > i) {
                    unsigned long long a = keys[i], b2 = keys[ixj];
                    bool up = ((i & k) == 0);
                    if ((up && a > b2) || (!up && a < b2)) { keys[i] = b2; keys[ixj] = a; }
                }
            }
            __syncthreads();
        }
    }

    unsigned long long thr = keys[NLIST - 1];   // candidate 129th smallest
    if (lv[7] < thr) sh_ok = 0;                 // this thread might hide a 9th element
    __syncthreads();

    if (sh_ok) {
        if (tid < NLIST) {
            unsigned long long key = keys[tid];
            rowlist[row * LSTRIDE + tid] =
                make_int2(__float_as_int(u2f((unsigned)(key >> 32))),
                          (int)(unsigned)(key & 0xFFFFFFFFull));
        }
        return;   // block-uniform
    }

    // ---- fallback: original exact 8-pass u64 radix-select ----
    if (tid == 0) { sh_prefix = 0ull; sh_rank = NLIST - 1; sh_cnt = 0; }
    __syncthreads();
    for (int d = 7; d >= 0; --d) {
        hist[tid] = 0;
        __syncthreads();
        unsigned long long pref = sh_prefix;
        int sh = (d + 1) * 8;
        for (int j = tid; j < NPRED; j += 256) {
            unsigned long long key = ((unsigned long long)f2u(crow[j]) << 32) | (unsigned)j;
            bool match = (sh >= 64) || ((key >> sh) == (pref >> sh));
            if (match) atomicAdd(&hist[(int)((key >> (d * 8)) & 255ull)], 1);
        }
        __syncthreads();
        if (tid == 0) {
            int rank = sh_rank, cum = 0, b = 0;
            for (; b < 256; ++b) { if (cum + hist[b] > rank) break; cum += hist[b]; }
            sh_prefix = pref | ((unsigned long long)b << (d * 8));
            sh_rank = rank - cum;
        }
        __syncthreads();
    }
    unsigned long long thr2 = sh_prefix;  // exact NLIST-th smallest key
    for (int j = tid; j < NPRED; j += 256) {
        unsigned long long key = ((unsigned long long)f2u(crow[j]) << 32) | (unsigned)j;
        if (key <= thr2) { int s = atomicAdd(&sh_cnt, 1); keys[s] = key; }
    }
    __syncthreads();
    if (tid >= sh_cnt) keys[tid] = ~0ull;
    __syncthreads();
    for (int k = 2; k <= 256; k <<= 1) {
        for (int j2 = k >> 1; j2 > 0; j2 >>= 1) {
            int i = tid, ixj = i ^ j2;
            if (ixj > i) {
                unsigned long long a = keys[i], b2 = keys[ixj];
                bool up = ((i & k) == 0);
                if ((up && a > b2) || (!up && a < b2)) { keys[i] = b2; keys[ixj] = a; }
            }
            __syncthreads();
        }
    }
    if (tid < NLIST) {
        unsigned long long key = keys[tid];
        rowlist[row * LSTRIDE + tid] =
            make_int2(__float_as_int(u2f((unsigned)(key >> 32))),
                      (int)(unsigned)(key & 0xFFFFFFFFull));
    }
}

// sparse JV LSA, single wave. Bit-identical to dense numpy JV (exact f64 op
// order, lex tie-breaks). ROUND-6 STRUCTURE RESTORED (241us measured; the
// round-7 register/shfl relocation regressed - single-wave barriers are ~free
// and uniform LDS broadcast reads beat shfl chains). One delta kept from
// round 7: the probe (pos,e0) is carried in registers and the NEXT row's
// rowlist load is issued in the bisv tail (after nr is known, before the
// barrier) - its L2 latency hides under the whole next V-scan + reduction.
// Safety: nr is never probed earlier in the same cur, so headpos[nr]'s last
// write was published by a prior epilogue barrier; same-wave LDS ordering
// covers lane-0's in-flight headpos[prow] write (different address).
__global__ __launch_bounds__(64) void k_lsa_sparse(
    const float* __restrict__ costT, const int2* __restrict__ rowlist,
    int* __restrict__ failFlag,
    unsigned* __restrict__ usedbits, int* __restrict__ out)
{
#pragma clang fp contract(off)
    __shared__ float  costV[NGT][VSLOT];   // [row][slot], 66KB; stride 129 -> conflict-free
    __shared__ double u_l[NGT];
    __shared__ int    c4r[NGT];
    __shared__ int    slot4row[NGT];
    __shared__ int    headpos[NGT];
    __shared__ int    colidV[VCAP];        // LDS mirror for lane-0 augment walk
    __shared__ int    pathV[VCAP], r4cV[VCAP];
    __shared__ int    SRr[VCAP];
    __shared__ double headv[VCAP];
    __shared__ int    headj[VCAP];
    __shared__ unsigned vbits[2048];

    int lane = threadIdx.x;
    for (int w = lane; w < 2048; w += 64) vbits[w] = 0u;
    for (int r = lane; r < NGT; r += 64) {
        u_l[r] = 0.0; c4r[r] = -1; slot4row[r] = -1; headpos[r] = 0;
    }
    // lane-owned slot state: slot k=lane -> *0, slot k=lane+64 -> *1
    double short0 = INFINITY, short1 = INFINITY;
    double v0 = 0.0, v1 = 0.0;
    int col0 = SENT_I, col1 = SENT_I;
    int sc0 = 0, sc1 = 0;
    int nV = 0;
    bool fail = false;
    __syncthreads();

    for (int cur = 0; cur < NGT && !fail; ++cur) {
        short0 = INFINITY; short1 = INFINITY; sc0 = 0; sc1 = 0;
        if (lane < nV)      pathV[lane]      = -1;
        if (lane + 64 < nV) pathV[lane + 64] = -1;
        if (lane == 0) SRr[0] = cur;
        int bi = cur, s = 1, pendrow = cur, pendpos = 0, sink = -1;
        double mv = 0.0, pendmv = 0.0;
        __syncthreads();
        // initial probe issue for row cur (completed inside the loop)
        int pos = headpos[cur];                   // uniform LDS broadcast
        int i0 = pos + lane;
        int2 e0 = (i0 < NLIST) ? rowlist[cur * LSTRIDE + i0] : make_int2(0, SENT_I);

        while (true) {
            int prow = pendrow;
            int pp   = pendpos;
            double pmv = pendmv;

            // ---- V-scan: register slot state + costV LDS read; candidates
            //      accumulate as fused (vkey, tkey) lexicographic keys ----
            double ui = u_l[bi];
            unsigned long long bvk = ~0ull, btk = ~0ull;
            if (lane < nV && !sc0) {
                double c = (double)costV[bi][lane];
                double r = ((mv + c) - ui) - v0;
                if (r < short0) { short0 = r; pathV[lane] = bi; }
                unsigned long long vk = d2u(short0);
                unsigned long long tk = ((unsigned long long)(unsigned)col0 << 32)
                                        | (0x80000000u | (unsigned)lane);
                if (vk < bvk || (vk == bvk && tk < btk)) { bvk = vk; btk = tk; }
            }
            int k1 = lane + 64;
            if (k1 < nV && !sc1) {
                double c = (double)costV[bi][k1];
                double r = ((mv + c) - ui) - v1;
                if (r < short1) { short1 = r; pathV[k1] = bi; }
                unsigned long long vk = d2u(short1);
                unsigned long long tk = ((unsigned long long)(unsigned)col1 << 32)
                                        | (0x80000000u | (unsigned)k1);
                if (vk < bvk || (vk == bvk && tk < btk)) { bvk = vk; btk = tk; }
            }
            // static heads merge (p==pendpos substituted from registers below)
            for (int p = lane; p < s; p += 64) {
                if (p == pp) continue;
                unsigned long long vk = d2u(headv[p]);
                unsigned long long tk = ((unsigned long long)(unsigned)headj[p] << 32)
                                        | (unsigned)p;
                if (vk < bvk || (vk == bvk && tk < btk)) { bvk = vk; btk = tk; }
            }

            // ---- probe completion (uniform register result) ----
            int hcol = SENT_I; float hval = 0.0f;
            {
                int c0 = e0.y;
                bool fresh = (i0 < NLIST) && !((vbits[c0 >> 5] >> (c0 & 31)) & 1u);
                unsigned long long m0 = __ballot(fresh);
                if (m0) {
                    int fl = __ffsll(m0) - 1;
                    hcol = __shfl(c0, fl, 64);
                    hval = __shfl(__int_as_float(e0.x), fl, 64);
                    pos += fl;
                } else {
                    pos += 64;
                    while (pos < NLIST) {
                        int i = pos + lane;
                        int2 e = (i < NLIST) ? rowlist[prow * LSTRIDE + i] : make_int2(0, SENT_I);
                        int c = e.y;
                        bool fr = (i < NLIST) && !((vbits[c >> 5] >> (c & 31)) & 1u);
                        unsigned long long m = __ballot(fr);
                        if (m) {
                            int fl = __ffsll(m) - 1;
                            hcol = __shfl(c, fl, 64);
                            hval = __shfl(__int_as_float(e.x), fl, 64);
                            pos += fl;
                            break;
                        }
                        pos += 64;
                    }
                }
            }
            double pend_headv = (hcol == SENT_I) ? (double)INFINITY
                                : ((pmv + (double)hval) - u_l[prow]);
            {
                unsigned long long vk = d2u(pend_headv);
                unsigned long long tk = ((unsigned long long)(unsigned)hcol << 32)
                                        | (unsigned)pp;
                if (vk < bvk || (vk == bvk && tk < btk)) { bvk = vk; btk = tk; }
            }

            // ---- fused lexicographic butterfly all-reduce (uniform result) ----
#pragma unroll
            for (int off = 1; off < 64; off <<= 1) {
                unsigned long long ov = __shfl_xor(bvk, off, 64);
                unsigned long long ot = __shfl_xor(btk, off, 64);
                if (ov < bvk || (ov == bvk && ot < btk)) { bvk = ov; btk = ot; }
            }
            double bv = u2d(bvk);
            unsigned tlow = (unsigned)btk;
            int bj   = (int)(btk >> 32);
            int bisv = (int)(tlow >> 31);
            int baux = (int)(tlow & 0x7FFFFFFFu);
            mv = bv;

            if (lane == 0) {
                headpos[prow] = pos;
                headv[pp] = pend_headv; headj[pp] = hcol;
            }
            if (bisv) {
                // owner lane marks its slot scanned (result uniform on all lanes)
                if ((baux & 63) == lane) {
                    if (baux & 64) sc1 = 1; else sc0 = 1;
                }
                int nr = r4cV[baux];           // uniform-address broadcast read
                if (lane == 0) SRr[s] = nr;
                pendrow = nr; pendpos = s; pendmv = bv; bi = nr; ++s;
                // prefetch next probe NOW: nr not yet probed this cur; its L2
                // latency hides under the entire next V-scan + reduction
                pos = headpos[nr];
                i0 = pos + lane;
                e0 = (i0 < NLIST) ? rowlist[nr * LSTRIDE + i0] : make_int2(0, SENT_I);
                __syncthreads();               // publish lane-0 writes for next iter
            } else {
                if (nV >= VCAP) {
                    fail = true;
                } else {
                    if ((nV & 63) == lane) {
                        if (nV & 64) { col1 = bj; v1 = 0.0; short1 = bv; sc1 = 1; }
                        else         { col0 = bj; v0 = 0.0; short0 = bv; sc0 = 1; }
                    }
                    if (lane == 0) {
                        colidV[nV] = bj;
                        pathV[nV] = SRr[baux]; r4cV[nV] = -1;
                        vbits[bj >> 5] |= (1u << (bj & 31));
                    }
                    sink = bj;
                    ++nV;
                }
                __syncthreads();               // publish sink writes for epilogue
                break;
            }
        }
        if (fail) break;

        // prefetch the new V column's 128 row costs; latency hides under epilogue
        int snew = nV - 1;
        float pfa = costT[(size_t)lane * NPRED + sink];
        float pfb = costT[(size_t)(lane + 64) * NPRED + sink];

        double mvf = mv;
        // register dual-variable update
        if (lane < nV && sc0)      v0 -= (mvf - short0);
        if (lane + 64 < nV && sc1) v1 -= (mvf - short1);

        // lane-parallel u_l updates for scanned rows (q in [1, s));
        // shortV gathered from owner lanes via shfl (uniform execution)
        {
            int q = lane;
            bool act = (q >= 1 && q < s);
            int i2 = act ? SRr[q] : 0;
            int sl = act ? slot4row[i2] : 0;
            double gA = __shfl(short0, sl & 63, 64);
            double gB = __shfl(short1, sl & 63, 64);
            double sv = (sl & 64) ? gB : gA;
            if (act) u_l[i2] += mvf - sv;
        }
        {
            int q = lane + 64;
            bool act = (q >= 1 && q < s);
            int i2 = act ? SRr[q] : 0;
            int sl = act ? slot4row[i2] : 0;
            double gA = __shfl(short0, sl & 63, 64);
            double gB = __shfl(short1, sl & 63, 64);
            double sv = (sl & 64) ? gB : gA;
            if (act) u_l[i2] += mvf - sv;
        }
        if (lane == 0) u_l[cur] += mvf;

        // serial augment walk (lane 0): reads pathV/colidV, updates assignment
        if (lane == 0) {
            int jslot = snew;
            while (true) {
                int i2 = pathV[jslot];
                r4cV[jslot] = i2;
                int oldslot = (c4r[i2] >= 0) ? slot4row[i2] : -1;
                c4r[i2] = colidV[jslot];
                slot4row[i2] = jslot;
                if (i2 == cur) break;
                jslot = oldslot;
            }
        }
        costV[lane][snew]      = pfa;
        costV[lane + 64][snew] = pfb;
        __syncthreads();   // publish costV/u_l/c4r/slot4row for next cur
    }

    if (lane == 0 && fail) *failFlag = 1;
    __syncthreads();
    if (!fail) {
        for (int w = lane; w < 2048; w += 64) usedbits[w] = 0u;
        __syncthreads();
        for (int r = lane; r < NGT; r += 64) {
            int p = c4r[r];
            atomicOr(&usedbits[p >> 5], 1u << (p & 31));
            out[r] = p;
            out[1408 + r] = r;
        }
    }
}

// dense fallback: only runs if k_lsa_sparse flagged overflow (should never happen)
__global__ __launch_bounds__(1024) void k_lsa_dense(
    const float* __restrict__ costT, const int* __restrict__ failFlag,
    double* __restrict__ v, double* __restrict__ shortest,
    int* __restrict__ path, int* __restrict__ row4col,
    unsigned char* __restrict__ SC, unsigned* __restrict__ usedbits,
    int* __restrict__ out)
{
#pragma clang fp contract(off)
    if (*failFlag == 0) return;
    __shared__ double u_l[NGT];
    __shared__ int    c4r[NGT];
    __shared__ int    SR[NGT + 1];
    __shared__ int    bi, bsink, nSR;
    __shared__ double bmin;
    __shared__ double wval[16];
    __shared__ int    widx[16];
    int tid = threadIdx.x;

    for (int j = tid; j < NPRED; j += 1024) { v[j] = 0.0; row4col[j] = -1; }
    if (tid < NGT) { u_l[tid] = 0.0; c4r[tid] = -1; }
    __syncthreads();

    for (int cur = 0; cur < NGT; ++cur) {
        for (int j = tid; j < NPRED; j += 1024) {
            shortest[j] = (double)INFINITY; path[j] = -1; SC[j] = 0;
        }
        if (tid == 0) { bi = cur; bsink = -1; bmin = 0.0; SR[0] = cur; nSR = 1; }
        __syncthreads();

        while (true) {
            int irow = bi;
            double mv = bmin;
            double ui = u_l[irow];
            const float* crow = costT + (size_t)irow * NPRED;
            double bestv = (double)INFINITY;
            int    bestj = SENT_I;
            for (int j = tid; j < NPRED; j += 1024) {
                if (!SC[j]) {
                    double s = shortest[j];
                    double r = ((mv + (double)crow[j]) - ui) - v[j];
                    if (r < s) { s = r; shortest[j] = r; path[j] = irow; }
                    if (s < bestv || (s == bestv && j < bestj)) { bestv = s; bestj = j; }
                }
            }
            for (int off = 32; off; off >>= 1) {
                double ov = __shfl_down(bestv, off, 64);
                int    oj = __shfl_down(bestj, off, 64);
                if (ov < bestv || (ov == bestv && oj < bestj)) { bestv = ov; bestj = oj; }
            }
            if ((tid & 63) == 0) { wval[tid >> 6] = bestv; widx[tid >> 6] = bestj; }
            __syncthreads();
            if (tid == 0) {
                double bv = wval[0]; int bj = widx[0];
                for (int w = 1; w < 16; ++w) {
                    double ov = wval[w]; int oj = widx[w];
                    if (ov < bv || (ov == bv && oj < bj)) { bv = ov; bj = oj; }
                }
                bmin = bv;
                SC[bj] = 1;
                int r = row4col[bj];
                if (r < 0) { bsink = bj; }
                else       { SR[nSR++] = r; bi = r; }
            }
            __syncthreads();
            if (bsink >= 0) break;
        }

        double mv = bmin;
        for (int j = tid; j < NPRED; j += 1024)
            if (SC[j]) v[j] -= (mv - shortest[j]);
        if (tid == 0) {
            u_l[cur] += mv;
            for (int k = 1; k < nSR; ++k) {
                int i2 = SR[k];
                u_l[i2] += mv - shortest[c4r[i2]];
            }
            int j = bsink;
            while (true) {
                int i2 = path[j];
                row4col[j] = i2;
                int nj = c4r[i2];
                c4r[i2] = j;
                j = nj;
                if (i2 == cur) break;
            }
        }
        __syncthreads();
    }

    for (int w = tid; w < 2048; w += 1024) usedbits[w] = 0u;
    __syncthreads();
    for (int j = tid; j < NPRED; j += 1024)
        if (row4col[j] >= 0) atomicOr(&usedbits[j >> 5], 1u << (j & 31));
    if (tid < NGT) {
        out[tid]        = c4r[tid];
        out[1408 + tid] = tid;
    }
}

// per-gt: histogram-select top >=KMIN by (val desc, idx asc), compact <=KEEP-1,
// bitonic-sort KEEP u64 keys in LDS, write sorted prefix.
__global__ __launch_bounds__(256) void k_prep(
    const int2* __restrict__ cpair, const int* __restrict__ ccnt,
    unsigned long long* __restrict__ scand, int* __restrict__ kcount,
    int* __restrict__ fullflag)
{
    __shared__ int hist[256];
    __shared__ unsigned long long keys[KEEP];
    __shared__ unsigned sh_pref, sh_thresh;
    __shared__ int sh_done, sh_fail, sh_cnt;
    int tid = threadIdx.x;
    int g = blockIdx.x;
    int nc = ccnt[g]; if (nc > CAP) nc = CAP;
    const int2* src = cpair + (size_t)g * CAP;

    unsigned thresh = 0;
    if (nc > KEEP - 1) {
        if (tid == 0) { sh_pref = 0; sh_done = 0; sh_fail = 0; }
        __syncthreads();
        int above = 0;
        for (int byt = 3; byt >= 0; --byt) {
            hist[tid] = 0;
            __syncthreads();
            unsigned pref = sh_pref;
            for (int c = tid; c < nc; c += 256) {
                unsigned u = f2u(__int_as_float(src[c].y));
                if (byt == 3 || (u >> ((byt + 1) * 8)) == (pref >> ((byt + 1) * 8)))
                    atomicAdd(&hist[(u >> (byt * 8)) & 255], 1);
            }
            __syncthreads();
            if (tid == 0) {
                int cum = 0, B = 0, kept = 0, abnew = above;
                for (int b = 255; b >= 0; --b) {
                    if (above + cum + hist[b] >= KMIN) {
                        B = b; kept = above + cum + hist[b]; abnew = above + cum; break;
                    }
                    cum += hist[b];
                }
                if (kept <= KEEP - 1) { sh_thresh = sh_pref | ((unsigned)B << (byt * 8)); sh_done = 1; }
                else {
                    above = abnew;
                    sh_pref = sh_pref | ((unsigned)B << (byt * 8));
                    if (byt == 0) sh_fail = 1;
                }
            }
            __syncthreads();
            if (sh_done || sh_fail) break;
        }
        if (sh_fail) {
            if (tid == 0) { fullflag[g] = 1; kcount[g] = 0; }
            return;
        }
        thresh = sh_thresh;
    }
    if (tid == 0) sh_cnt = 0;
    __syncthreads();
    for (int c = tid; c < nc; c += 256) {
        unsigned u = f2u(__int_as_float(src[c].y));
        if (u >= thresh) {
            int slot = atomicAdd(&sh_cnt, 1);
            keys[slot] = ((unsigned long long)(~u) << 32) | (unsigned)src[c].x;
        }
    }
    __syncthreads();
    int kept = sh_cnt;
    for (int i = tid; i < KEEP; i += 256) if (i >= kept) keys[i] = ~0ull;
    __syncthreads();
    for (int k = 2; k <= KEEP; k <<= 1) {
        for (int j = k >> 1; j > 0; j >>= 1) {
            for (int i = tid; i < KEEP; i += 256) {
                int ixj = i ^ j;
                if (ixj > i) {
                    unsigned long long a = keys[i], b = keys[ixj];
                    bool up = ((i & k) == 0);
                    if ((up && a > b) || (!up && a < b)) { keys[i] = b; keys[ixj] = a; }
                }
            }
            __syncthreads();
        }
    }
    for (int i = tid; i < KEEP; i += 256) scand[(size_t)g * KEEP + i] = keys[i];
    if (tid == 0) { kcount[g] = kept; fullflag[g] = 0; }
}

// sequential dynamic assignment, single wave
__global__ __launch_bounds__(64) void k_dyn2(
    const int* __restrict__ order, const int* __restrict__ kcount,
    const unsigned long long* __restrict__ scand, const int* __restrict__ fullflag,
    const int* __restrict__ ccnt, const int2* __restrict__ cpair,
    const unsigned* __restrict__ usedbits_g, const int* __restrict__ failFlag,
    int* __restrict__ out)
{
    __shared__ unsigned bits[2048];
    int lane = threadIdx.x;
    for (int w = lane; w < 2048; w += 64) bits[w] = usedbits_g[w];
    __syncthreads();
    bool globalFull = (*failFlag != 0);

    for (int k = 0; k < NGT; ++k) {
        int gt = order[k];
        int got = 0;
        if (!globalFull && fullflag[gt] == 0) {
            int kept = kcount[gt];
            int base = 0;
            while (got < 10 && base < kept) {
                int i = base + lane;
                unsigned long long key = (i < kept) ? scand[(size_t)gt * KEEP + i] : ~0ull;
                int p = (int)(unsigned)(key & 0xFFFFFFFFull);
                bool ok = (key != ~0ull) && !((bits[p >> 5] >> (p & 31)) & 1u);
                unsigned long long mask = __ballot(ok);
                int need = 10 - got;
                int pre = __popcll(mask & ((1ull << lane) - 1ull));
                if (ok && pre < need) {
                    out[128 + k * 10 + got + pre] = p;
                    out[1408 + 128 + k * 10 + got + pre] = gt;
                    atomicOr(&bits[p >> 5], 1u << (p & 31));
                }
                int tot = __popcll(mask);
                got += (tot < need) ? tot : need;
                base += 64;
                __syncthreads();
            }
        } else {
            int nc = ccnt[gt]; if (nc > CAP) nc = CAP;
            float lv[10]; int li[10];
#pragma unroll
            for (int q = 0; q < 10; ++q) { lv[q] = -1e30f; li[q] = SENT_I; }
            for (int c = lane; c < nc; c += 64) {
                int2 pr = cpair[(size_t)gt * CAP + c];
                int p = pr.x;
                if ((bits[p >> 5] >> (p & 31)) & 1u) continue;
                float cv = __int_as_float(pr.y); int ci = p;
#pragma unroll
                for (int q = 0; q < 10; ++q) {
                    bool b = (cv > lv[q]) || (cv == lv[q] && ci < li[q]);
                    float tv = b ? lv[q] : cv; int ti = b ? li[q] : ci;
                    if (b) { lv[q] = cv; li[q] = ci; }
                    cv = tv; ci = ti;
                }
            }
#pragma unroll
            for (int q = 0; q < 10; ++q) {
                float mo = lv[0]; int mj = li[0];
#pragma unroll
                for (int off = 1; off < 64; off <<= 1) {
                    float ov = __shfl_xor(mo, off, 64);
                    int oj = __shfl_xor(mj, off, 64);
                    if (ov > mo || (ov == mo && oj < mj)) { mo = ov; mj = oj; }
                }
                bool valid = (mj != SENT_I);
                if (valid && li[0] == mj) {
#pragma unroll
                    for (int t = 0; t < 9; ++t) { lv[t] = lv[t + 1]; li[t] = li[t + 1]; }
                    lv[9] = -1e30f; li[9] = SENT_I;
                }
                if (lane == q) {
                    out[128 + k * 10 + q] = valid ? mj : -1;
                    out[1408 + 128 + k * 10 + q] = valid ? gt : -1;
                    if (valid) atomicOr(&bits[mj >> 5], 1u << (mj & 31));
                }
            }
            got = 10;
            __syncthreads();
        }
        for (int q = got + lane; q < 10; q += 64) {
            out[128 + k * 10 + q] = -1;
            out[1408 + 128 + k * 10 + q] = -1;
        }
        __syncthreads();
    }
}

// ---------- launch ----------

extern "C" void kernel_launch(void* const* d_in, const int* in_sizes, int n_in,
                              void* d_out, int out_size, void* d_ws, size_t ws_size,
                              hipStream_t stream) {
    const float* pc  = (const float*)d_in[0];
    const float* ps  = (const float*)d_in[1];
    const float* cls = (const float*)d_in[2];
    const float* gc  = (const float*)d_in[4];
    const float* gs  = (const float*)d_in[5];
    const int*   lab = (const int*)d_in[6];

    char* ws = (char*)d_ws;
    float*         costT    = (float*)(ws + 0);                  // 33,554,432
    unsigned long long* scand = (unsigned long long*)(ws + 0);   //  2,097,152 (over costT; k_prep runs after LSA)
    int2*          rowlist  = (int2*)(ws + 33554432);            //    135,168 (over v)
    double*        v        = (double*)(ws + 33554432);          //    524,288 (fallback only)
    double*        shortest = (double*)(ws + 34078720);          //    524,288 (fallback only)
    int*           path     = (int*)(ws + 34603008);             //    262,144 (fallback only)
    int*           row4col  = (int*)(ws + 34865152);             //    262,144 (fallback only)
    unsigned char* SC       = (unsigned char*)(ws + 35127296);   //     65,536 (fallback only)
    int*           kcount   = (int*)(ws + 35192832);
    int*           fullflag = (int*)(ws + 35193344);
    int*           ccnt     = (int*)(ws + 35193856);
    unsigned*      cmax     = (unsigned*)(ws + 35194368);
    int*           order    = (int*)(ws + 35194880);
    int*           failFlag = (int*)(ws + 35195392);
    unsigned*      usedbits = (unsigned*)(ws + 35195904);        //      8,192
    int2*          cpair    = (int2*)(ws + 35204096);            // 12,582,912 -> end 47,787,008

    int* out = (int*)d_out;

    hipLaunchKernelGGL(k_gather, dim3(NPRED / 64), dim3(256), 0, stream,
                       cls, lab, costT, ccnt, cmax, failFlag);
    hipLaunchKernelGGL(k_cost, dim3((NPRED / 256) * GSPLIT), dim3(256), 0, stream,
                       pc, ps, gc, gs, costT, ccnt, cmax, cpair);
    hipLaunchKernelGGL(k_toprow, dim3(NGT + 1), dim3(256), 0, stream,
                       costT, rowlist, cmax, order);
    hipLaunchKernelGGL(k_lsa_sparse, dim3(1), dim3(64), 0, stream,
                       costT, rowlist, failFlag, usedbits, out);
    hipLaunchKernelGGL(k_lsa_dense, dim3(1), dim3(1024), 0, stream,
                       costT, failFlag, v, shortest, path, row4col, SC, usedbits, out);
    hipLaunchKernelGGL(k_prep, dim3(NGT), dim3(256), 0, stream,
                       cpair, ccnt, scand, kcount, fullflag);
    hipLaunchKernelGGL(k_dyn2, dim3(1), dim3(64), 0, stream,
                       order, kcount, scand, fullflag, ccnt, cpair, usedbits, failFlag, out);
}

// Round 10
// 662.798 us; speedup vs baseline: 1.0416x; 1.0416x over previous
//
#include <hip/hip_runtime.h>
#include <hip/hip_bf16.h>
#include <math.h>

#define NPRED 65536
#define NGT   128
#define NCLS  256
#define CAP   12288
#define VCAP  160
#define VSLOT 129    // costV inner stride: >=128 slots, 129 for conflict-free column writes
#define NLIST 129    // per-row sorted prefix: 128 (max |V|) + 1 guarantees a fresh head
#define LSTRIDE 132
#define KEEP  2048
#define KMIN  1418
#define GSPLIT 4     // k_cost g-split: 4 blocks of 32 gts per 256-pred slab
#define GPB   (NGT / GSPLIT)
#define NCAND 4096   // k_toprow candidates: 512 threads x top-8
#define SENT_I 0x7FFFFFFF

// ---------- numeric helpers (match reference op order; no FMA contraction) ----------

// monotone map f32 -> uint32 (order-preserving for all floats)
__device__ __forceinline__ unsigned f2u(float f) {
    unsigned u = __float_as_uint(f);
    return (u & 0x80000000u) ? ~u : (u | 0x80000000u);
}
__device__ __forceinline__ float u2f(unsigned x) {
    unsigned u = (x & 0x80000000u) ? (x ^ 0x80000000u) : ~x;
    return __uint_as_float(u);
}
// monotone map f64 -> uint64 (order-preserving; used for packed LSA reduction)
__device__ __forceinline__ unsigned long long d2u(double d) {
    unsigned long long u = (unsigned long long)__double_as_longlong(d);
    return (u & 0x8000000000000000ull) ? ~u : (u | 0x8000000000000000ull);
}
__device__ __forceinline__ double u2d(unsigned long long x) {
    unsigned long long u = (x & 0x8000000000000000ull) ? (x ^ 0x8000000000000000ull) : ~x;
    return __longlong_as_double((long long)u);
}

__device__ __forceinline__ float giou3d(
    float pl0, float pl1, float pl2, float ph0, float ph1, float ph2, float pvol,
    float gl0, float gl1, float gl2, float gh0, float gh1, float gh2, float gvol)
{
#pragma clang fp contract(off)
    float c0 = fmaxf(fminf(ph0, gh0) - fmaxf(pl0, gl0), 0.0f);
    float c1 = fmaxf(fminf(ph1, gh1) - fmaxf(pl1, gl1), 0.0f);
    float c2 = fmaxf(fminf(ph2, gh2) - fmaxf(pl2, gl2), 0.0f);
    float overlap = (c0 * c1) * c2;
    float uni = fmaxf((pvol + gvol) - overlap, 1e-6f);
    float iou = overlap / uni;
    float e0 = fmaxf(fmaxf(ph0, gh0) - fminf(pl0, gl0), 0.0f);
    float e1 = fmaxf(fmaxf(ph1, gh1) - fminf(pl1, gl1), 0.0f);
    float e2 = fmaxf(fmaxf(ph2, gh2) - fminf(pl2, gl2), 0.0f);
    float enc = fmaxf((e0 * e1) * e2, 1e-6f);
    return iou - (enc - uni) / enc;
}

// ---------- kernels ----------

// coalesced cls load + LDS transpose + sigmoid: costT[g][p] = -sigmoid(cls[p][lab[g]])
// block 0 also performs the (former k_init) counter zeroing - no later-kernel hazard.
__global__ __launch_bounds__(256) void k_gather(
    const float* __restrict__ cls, const int* __restrict__ lab,
    float* __restrict__ costT,
    int* __restrict__ ccnt, unsigned* __restrict__ cmax, int* __restrict__ failFlag)
{
#pragma clang fp contract(off)
    __shared__ float tile[64][NCLS + 1];
    __shared__ int labl[NGT];
    int tid = threadIdx.x;
    int p0 = blockIdx.x * 64;
    if (blockIdx.x == 0) {
        if (tid < NGT) { ccnt[tid] = 0; cmax[tid] = 0u; }
        if (tid == 0) *failFlag = 0;
    }
    if (tid < NGT) labl[tid] = lab[tid];
    for (int it = 0; it < 16; ++it) {
        int row = it * 4 + (tid >> 6);
        int col = (tid & 63) * 4;
        const float4 v = *(const float4*)&cls[(size_t)(p0 + row) * NCLS + col];
        tile[row][col + 0] = v.x; tile[row][col + 1] = v.y;
        tile[row][col + 2] = v.z; tile[row][col + 3] = v.w;
    }
    __syncthreads();
    int lane = tid & 63;
    for (int rep = 0; rep < 32; ++rep) {
        int g = rep * 4 + (tid >> 6);
        float val = tile[lane][labl[g]];
        double s = 1.0 / (1.0 + exp(-(double)val));
        costT[(size_t)g * NPRED + p0 + lane] = -(float)s;
    }
}

// two-pass, block-aggregated atomics. Grid: (NPRED/256)*GSPLIT blocks x 256 thr.
// Block handles 256 preds x GPB gts. Pass A: giou + LDS max/count + costT RMW;
// per-thread giou kept in registers (gior) so Pass B skips the recompute.
__global__ __launch_bounds__(256) void k_cost(
    const float* __restrict__ pc, const float* __restrict__ ps,
    const float* __restrict__ gc, const float* __restrict__ gs,
    float* __restrict__ costT, int* __restrict__ ccnt, unsigned* __restrict__ cmax,
    int2* __restrict__ cpair)
{
#pragma clang fp contract(off)
    __shared__ float gb[GPB][6];
    __shared__ float gvol[GPB];
    __shared__ unsigned smax[GPB];
    __shared__ int cntl[GPB], basel[GPB], curl[GPB];
    int tid = threadIdx.x;
    int lane = tid & 63;
    int g0 = (blockIdx.x & (GSPLIT - 1)) * GPB;
    int p  = (blockIdx.x >> 2) * 256 + tid;

    if (tid < GPB) {
        int g = g0 + tid;
        float c0 = gc[g * 3 + 0], c1 = gc[g * 3 + 1], c2 = gc[g * 3 + 2];
        float s0 = gs[g * 3 + 0], s1 = gs[g * 3 + 1], s2 = gs[g * 3 + 2];
        float l0 = c0 - s0 / 2.0f, l1 = c1 - s1 / 2.0f, l2 = c2 - s2 / 2.0f;
        float h0 = c0 + s0 / 2.0f, h1 = c1 + s1 / 2.0f, h2 = c2 + s2 / 2.0f;
        gb[tid][0] = l0; gb[tid][1] = l1; gb[tid][2] = l2;
        gb[tid][3] = h0; gb[tid][4] = h1; gb[tid][5] = h2;
        gvol[tid] = ((h0 - l0) * (h1 - l1)) * (h2 - l2);
        smax[tid] = 0u; cntl[tid] = 0; curl[tid] = 0;
    }
    __syncthreads();

    float c0 = pc[p * 3 + 0], c1 = pc[p * 3 + 1], c2 = pc[p * 3 + 2];
    float s0 = ps[p * 3 + 0], s1 = ps[p * 3 + 1], s2 = ps[p * 3 + 2];
    float pl0 = c0 - s0 / 2.0f, pl1 = c1 - s1 / 2.0f, pl2 = c2 - s2 / 2.0f;
    float ph0 = c0 + s0 / 2.0f, ph1 = c1 + s1 / 2.0f, ph2 = c2 + s2 / 2.0f;
    float pvol = ((ph0 - pl0) * (ph1 - pl1)) * (ph2 - pl2);

    float gior[GPB];   // fully-unrolled static indexing -> stays in VGPRs

    // Pass A: no blocking global atomics in the loop
#pragma unroll
    for (int gg = 0; gg < GPB; ++gg) {
        float gio = giou3d(pl0, pl1, pl2, ph0, ph1, ph2, pvol,
                           gb[gg][0], gb[gg][1], gb[gg][2], gb[gg][3], gb[gg][4], gb[gg][5],
                           gvol[gg]);
        gior[gg] = gio;
        float m = gio;
        for (int off = 32; off; off >>= 1) m = fmaxf(m, __shfl_xor(m, off, 64));
        unsigned long long mask = __ballot(gio > 0.25f);
        if (lane == 0) {
            atomicMax(&smax[gg], f2u(m));
            atomicAdd(&cntl[gg], __popcll(mask));
        }
        size_t ij = (size_t)(g0 + gg) * NPRED + p;
        float ns = costT[ij];                 // staged -sigmoid
        costT[ij] = ns + (2.0f * (-gio));     // == (-sg) + (2.0f*(-gio))
    }
    __syncthreads();
    // one parallel global atomic per gt (32 concurrent RTs); cmax fire-and-forget
    if (tid < GPB) {
        atomicMax(&cmax[g0 + tid], smax[tid]);
        basel[tid] = atomicAdd(&ccnt[g0 + tid], cntl[tid]);
    }
    __syncthreads();

    // Pass B: scatter candidates from register-cached giou (bit-identical values)
#pragma unroll
    for (int gg = 0; gg < GPB; ++gg) {
        float gio = gior[gg];
        bool cand = (gio > 0.25f);
        unsigned long long mask = __ballot(cand);
        int cnt = __popcll(mask);
        int wo = 0;
        if (lane == 0 && cnt) wo = atomicAdd(&curl[gg], cnt);
        wo = __shfl(wo, 0, 64);
        if (cand) {
            int slot = basel[gg] + wo + __popcll(mask & ((1ull << lane) - 1ull));
            if (slot < CAP)
                cpair[(size_t)(g0 + gg) * CAP + slot] = make_int2(p, __float_as_int(gio));
        }
    }
}

// per-row exact top-NLIST smallest (value, col), sorted ascending by (val, col).
// Rebuilt fast path: 512 threads, per-thread top-8 over 128 elements with
// 4-deep load batching (MLP), 4096 candidates in LDS, 8-pass radix-SELECT of
// the exact 129th-smallest candidate key t (replaces the 66-stage bitonic
// sort of 2048), compact the exactly-129 keys <= t, bitonic-sort 256, write.
// Exactness: a thread whose 8th-smallest < t could hide a 9th element below t
// -> per-row fallback to the exact full-row radix select (P ~ 1e-11/thread).
// Block NGT (the +1 block) performs the former k_sort rank-sort of cmax.
__global__ __launch_bounds__(512) void k_toprow(
    const float* __restrict__ costT, int2* __restrict__ rowlist,
    const unsigned* __restrict__ cmax, int* __restrict__ order)
{
    __shared__ unsigned long long keys[NCAND];   // 32 KB candidates
    __shared__ unsigned long long cbuf[256];     // compacted winners
    __shared__ int hist[256];
    __shared__ unsigned long long sh_prefix;
    __shared__ int sh_rank, sh_cnt, sh_ok;
    __shared__ unsigned msort[NGT];
    int tid = threadIdx.x;
    int row = blockIdx.x;

    if (row == NGT) {   // fused k_sort (independent of toprow work)
        if (tid < NGT) msort[tid] = cmax[tid];
        __syncthreads();
        if (tid < NGT) {
            unsigned mt = msort[tid];
            int r = 0;
            for (int k = 0; k < NGT; ++k) {
                unsigned mk = msort[k];
                if (mk < mt || (mk == mt && k < tid)) r++;
            }
            order[r] = tid;
        }
        return;
    }
    const float* crow = costT + (size_t)row * NPRED;
    const float4* crow4 = (const float4*)crow;

    // ---- scan: per-thread top-8 (sorted ascending in registers) ----
    unsigned long long lv[8];
#pragma unroll
    for (int q = 0; q < 8; ++q) lv[q] = ~0ull;
    auto ins4 = [&](float4 v4, int j) {
        float vv[4] = {v4.x, v4.y, v4.z, v4.w};
#pragma unroll
        for (int e = 0; e < 4; ++e) {
            unsigned long long key =
                ((unsigned long long)f2u(vv[e]) << 32) | (unsigned)(j + e);
            if (key < lv[7]) {
                unsigned long long c = key;
#pragma unroll
                for (int q = 0; q < 8; ++q) {
                    unsigned long long mx = (c > lv[q]) ? c : lv[q];
                    unsigned long long mn = (c > lv[q]) ? lv[q] : c;
                    lv[q] = mn; c = mx;
                }
            }
        }
    };
    for (int base = 0; base < 32; base += 4) {   // 4 independent loads in flight
        float4 va = crow4[tid + (base + 0) * 512];
        float4 vb = crow4[tid + (base + 1) * 512];
        float4 vc = crow4[tid + (base + 2) * 512];
        float4 vd = crow4[tid + (base + 3) * 512];
        ins4(va, (tid + (base + 0) * 512) * 4);
        ins4(vb, (tid + (base + 1) * 512) * 4);
        ins4(vc, (tid + (base + 2) * 512) * 4);
        ins4(vd, (tid + (base + 3) * 512) * 4);
    }
#pragma unroll
    for (int q = 0; q < 8; ++q) keys[tid * 8 + q] = lv[q];
    if (tid == 0) { sh_ok = 1; sh_prefix = 0ull; sh_rank = NLIST - 1; sh_cnt = 0; }
    __syncthreads();

    // ---- 8-pass radix select over the 4096 candidates: t = 129th smallest ----
    for (int d = 7; d >= 0; --d) {
        if (tid < 256) hist[tid] = 0;
        __syncthreads();
        unsigned long long pref = sh_prefix;
        int sh = (d + 1) * 8;
        for (int i = tid; i < NCAND; i += 512) {
            unsigned long long key = keys[i];
            bool match = (sh >= 64) || ((key >> sh) == (pref >> sh));
            if (match) atomicAdd(&hist[(int)((key >> (d * 8)) & 255ull)], 1);
        }
        __syncthreads();
        if (tid == 0) {
            int rank = sh_rank, cum = 0, b = 0;
            for (; b < 256; ++b) { if (cum + hist[b] > rank) break; cum += hist[b]; }
            sh_prefix = pref | ((unsigned long long)b << (d * 8));
            sh_rank = rank - cum;
        }
        __syncthreads();
    }
    unsigned long long t = sh_prefix;   // exact 129th-smallest candidate key
    if (lv[7] < t) sh_ok = 0;           // this thread might hide a 9th element
    __syncthreads();
    bool ok = (sh_ok != 0);             // block-uniform

    if (ok) {
        // compact the exactly-NLIST keys <= t from the candidate pool
        for (int i = tid; i < NCAND; i += 512) {
            unsigned long long key = keys[i];
            if (key <= t) { int s2 = atomicAdd(&sh_cnt, 1); cbuf[s2] = key; }
        }
        __syncthreads();
    } else {
        // ---- fallback: exact full-row 8-pass u64 radix-select (rare) ----
        if (tid == 0) { sh_prefix = 0ull; sh_rank = NLIST - 1; sh_cnt = 0; }
        __syncthreads();
        for (int d = 7; d >= 0; --d) {
            if (tid < 256) hist[tid] = 0;
            __syncthreads();
            unsigned long long pref = sh_prefix;
            int sh = (d + 1) * 8;
            for (int j = tid; j < NPRED; j += 512) {
                unsigned long long key = ((unsigned long long)f2u(crow[j]) << 32) | (unsigned)j;
                bool match = (sh >= 64) || ((key >> sh) == (pref >> sh));
                if (match) atomicAdd(&hist[(int)((key >> (d * 8)) & 255ull)], 1);
            }
            __syncthreads();
            if (tid == 0) {
                int rank = sh_rank, cum = 0, b = 0;
                for (; b < 256; ++b) { if (cum + hist[b] > rank) break; cum += hist[b]; }
                sh_prefix = pref | ((unsigned long long)b << (d * 8));
                sh_rank = rank - cum;
            }
            __syncthreads();
        }
        unsigned long long thr2 = sh_prefix;  // exact NLIST-th smallest key
        for (int j = tid; j < NPRED; j += 512) {
            unsigned long long key = ((unsigned long long)f2u(crow[j]) << 32) | (unsigned)j;
            if (key <= thr2) { int s2 = atomicAdd(&sh_cnt, 1); cbuf[s2] = key; }
        }
        __syncthreads();
    }

    // ---- pad to 256, bitonic sort ascending, write sorted NLIST prefix ----
    int kept = sh_cnt;
    if (tid < 256 && tid >= kept) cbuf[tid] = ~0ull;
    __syncthreads();
    for (int k = 2; k <= 256; k <<= 1) {
        for (int j2 = k >> 1; j2 > 0; j2 >>= 1) {
            if (tid < 256) {
                int i = tid, ixj = i ^ j2;
                if (ixj > i) {
                    unsigned long long a = cbuf[i], b2 = cbuf[ixj];
                    bool up = ((i & k) == 0);
                    if ((up && a > b2) || (!up && a < b2)) { cbuf[i] = b2; cbuf[ixj] = a; }
                }
            }
            __syncthreads();
        }
    }
    if (tid < NLIST) {
        unsigned long long key = cbuf[tid];
        rowlist[row * LSTRIDE + tid] =
            make_int2(__float_as_int(u2f((unsigned)(key >> 32))),
                      (int)(unsigned)(key & 0xFFFFFFFFull));
    }
}

// sparse JV LSA, single wave. Bit-identical to dense numpy JV (exact f64 op
// order, lex tie-breaks). Round-8 version unchanged (measured 240us, absmax 0).
__global__ __launch_bounds__(64) void k_lsa_sparse(
    const float* __restrict__ costT, const int2* __restrict__ rowlist,
    int* __restrict__ failFlag,
    unsigned* __restrict__ usedbits, int* __restrict__ out)
{
#pragma clang fp contract(off)
    __shared__ float  costV[NGT][VSLOT];   // [row][slot], 66KB; stride 129 -> conflict-free
    __shared__ double u_l[NGT];
    __shared__ int    c4r[NGT];
    __shared__ int    slot4row[NGT];
    __shared__ int    headpos[NGT];
    __shared__ int    colidV[VCAP];        // LDS mirror for lane-0 augment walk
    __shared__ int    pathV[VCAP], r4cV[VCAP];
    __shared__ int    SRr[VCAP];
    __shared__ double headv[VCAP];
    __shared__ int    headj[VCAP];
    __shared__ unsigned vbits[2048];

    int lane = threadIdx.x;
    for (int w = lane; w < 2048; w += 64) vbits[w] = 0u;
    for (int r = lane; r < NGT; r += 64) {
        u_l[r] = 0.0; c4r[r] = -1; slot4row[r] = -1; headpos[r] = 0;
    }
    // lane-owned slot state: slot k=lane -> *0, slot k=lane+64 -> *1
    double short0 = INFINITY, short1 = INFINITY;
    double v0 = 0.0, v1 = 0.0;
    int col0 = SENT_I, col1 = SENT_I;
    int sc0 = 0, sc1 = 0;
    int nV = 0;
    bool fail = false;
    __syncthreads();

    for (int cur = 0; cur < NGT && !fail; ++cur) {
        short0 = INFINITY; short1 = INFINITY; sc0 = 0; sc1 = 0;
        if (lane < nV)      pathV[lane]      = -1;
        if (lane + 64 < nV) pathV[lane + 64] = -1;
        if (lane == 0) SRr[0] = cur;
        int bi = cur, s = 1, pendrow = cur, pendpos = 0, sink = -1;
        double mv = 0.0, pendmv = 0.0;
        __syncthreads();
        // initial probe issue for row cur (completed inside the loop)
        int pos = headpos[cur];                   // uniform LDS broadcast
        int i0 = pos + lane;
        int2 e0 = (i0 < NLIST) ? rowlist[cur * LSTRIDE + i0] : make_int2(0, SENT_I);

        while (true) {
            int prow = pendrow;
            int pp   = pendpos;
            double pmv = pendmv;

            // ---- V-scan: register slot state + costV LDS read; candidates
            //      accumulate as fused (vkey, tkey) lexicographic keys ----
            double ui = u_l[bi];
            unsigned long long bvk = ~0ull, btk = ~0ull;
            if (lane < nV && !sc0) {
                double c = (double)costV[bi][lane];
                double r = ((mv + c) - ui) - v0;
                if (r < short0) { short0 = r; pathV[lane] = bi; }
                unsigned long long vk = d2u(short0);
                unsigned long long tk = ((unsigned long long)(unsigned)col0 << 32)
                                        | (0x80000000u | (unsigned)lane);
                if (vk < bvk || (vk == bvk && tk < btk)) { bvk = vk; btk = tk; }
            }
            int k1 = lane + 64;
            if (k1 < nV && !sc1) {
                double c = (double)costV[bi][k1];
                double r = ((mv + c) - ui) - v1;
                if (r < short1) { short1 = r; pathV[k1] = bi; }
                unsigned long long vk = d2u(short1);
                unsigned long long tk = ((unsigned long long)(unsigned)col1 << 32)
                                        | (0x80000000u | (unsigned)k1);
                if (vk < bvk || (vk == bvk && tk < btk)) { bvk = vk; btk = tk; }
            }
            // static heads merge (p==pendpos substituted from registers below)
            for (int p = lane; p < s; p += 64) {
                if (p == pp) continue;
                unsigned long long vk = d2u(headv[p]);
                unsigned long long tk = ((unsigned long long)(unsigned)headj[p] << 32)
                                        | (unsigned)p;
                if (vk < bvk || (vk == bvk && tk < btk)) { bvk = vk; btk = tk; }
            }

            // ---- probe completion (uniform register result) ----
            int hcol = SENT_I; float hval = 0.0f;
            {
                int c0 = e0.y;
                bool fresh = (i0 < NLIST) && !((vbits[c0 >> 5] >> (c0 & 31)) & 1u);
                unsigned long long m0 = __ballot(fresh);
                if (m0) {
                    int fl = __ffsll(m0) - 1;
                    hcol = __shfl(c0, fl, 64);
                    hval = __shfl(__int_as_float(e0.x), fl, 64);
                    pos += fl;
                } else {
                    pos += 64;
                    while (pos < NLIST) {
                        int i = pos + lane;
                        int2 e = (i < NLIST) ? rowlist[prow * LSTRIDE + i] : make_int2(0, SENT_I);
                        int c = e.y;
                        bool fr = (i < NLIST) && !((vbits[c >> 5] >> (c & 31)) & 1u);
                        unsigned long long m = __ballot(fr);
                        if (m) {
                            int fl = __ffsll(m) - 1;
                            hcol = __shfl(c, fl, 64);
                            hval = __shfl(__int_as_float(e.x), fl, 64);
                            pos += fl;
                            break;
                        }
                        pos += 64;
                    }
                }
            }
            double pend_headv = (hcol == SENT_I) ? (double)INFINITY
                                : ((pmv + (double)hval) - u_l[prow]);
            {
                unsigned long long vk = d2u(pend_headv);
                unsigned long long tk = ((unsigned long long)(unsigned)hcol << 32)
                                        | (unsigned)pp;
                if (vk < bvk || (vk == bvk && tk < btk)) { bvk = vk; btk = tk; }
            }

            // ---- fused lexicographic butterfly all-reduce (uniform result) ----
#pragma unroll
            for (int off = 1; off < 64; off <<= 1) {
                unsigned long long ov = __shfl_xor(bvk, off, 64);
                unsigned long long ot = __shfl_xor(btk, off, 64);
                if (ov < bvk || (ov == bvk && ot < btk)) { bvk = ov; btk = ot; }
            }
            double bv = u2d(bvk);
            unsigned tlow = (unsigned)btk;
            int bj   = (int)(btk >> 32);
            int bisv = (int)(tlow >> 31);
            int baux = (int)(tlow & 0x7FFFFFFFu);
            mv = bv;

            if (lane == 0) {
                headpos[prow] = pos;
                headv[pp] = pend_headv; headj[pp] = hcol;
            }
            if (bisv) {
                // owner lane marks its slot scanned (result uniform on all lanes)
                if ((baux & 63) == lane) {
                    if (baux & 64) sc1 = 1; else sc0 = 1;
                }
                int nr = r4cV[baux];           // uniform-address broadcast read
                if (lane == 0) SRr[s] = nr;
                pendrow = nr; pendpos = s; pendmv = bv; bi = nr; ++s;
                // prefetch next probe NOW: nr not yet probed this cur; its L2
                // latency hides under the entire next V-scan + reduction
                pos = headpos[nr];
                i0 = pos + lane;
                e0 = (i0 < NLIST) ? rowlist[nr * LSTRIDE + i0] : make_int2(0, SENT_I);
                __syncthreads();               // publish lane-0 writes for next iter
            } else {
                if (nV >= VCAP) {
                    fail = true;
                } else {
                    if ((nV & 63) == lane) {
                        if (nV & 64) { col1 = bj; v1 = 0.0; short1 = bv; sc1 = 1; }
                        else         { col0 = bj; v0 = 0.0; short0 = bv; sc0 = 1; }
                    }
                    if (lane == 0) {
                        colidV[nV] = bj;
                        pathV[nV] = SRr[baux]; r4cV[nV] = -1;
                        vbits[bj >> 5] |= (1u << (bj & 31));
                    }
                    sink = bj;
                    ++nV;
                }
                __syncthreads();               // publish sink writes for epilogue
                break;
            }
        }
        if (fail) break;

        // prefetch the new V column's 128 row costs; latency hides under epilogue
        int snew = nV - 1;
        float pfa = costT[(size_t)lane * NPRED + sink];
        float pfb = costT[(size_t)(lane + 64) * NPRED + sink];

        double mvf = mv;
        // register dual-variable update
        if (lane < nV && sc0)      v0 -= (mvf - short0);
        if (lane + 64 < nV && sc1) v1 -= (mvf - short1);

        // lane-parallel u_l updates for scanned rows (q in [1, s));
        // shortV gathered from owner lanes via shfl (uniform execution)
        {
            int q = lane;
            bool act = (q >= 1 && q < s);
            int i2 = act ? SRr[q] : 0;
            int sl = act ? slot4row[i2] : 0;
            double gA = __shfl(short0, sl & 63, 64);
            double gB = __shfl(short1, sl & 63, 64);
            double sv = (sl & 64) ? gB : gA;
            if (act) u_l[i2] += mvf - sv;
        }
        {
            int q = lane + 64;
            bool act = (q >= 1 && q < s);
            int i2 = act ? SRr[q] : 0;
            int sl = act ? slot4row[i2] : 0;
            double gA = __shfl(short0, sl & 63, 64);
            double gB = __shfl(short1, sl & 63, 64);
            double sv = (sl & 64) ? gB : gA;
            if (act) u_l[i2] += mvf - sv;
        }
        if (lane == 0) u_l[cur] += mvf;

        // serial augment walk (lane 0): reads pathV/colidV, updates assignment
        if (lane == 0) {
            int jslot = snew;
            while (true) {
                int i2 = pathV[jslot];
                r4cV[jslot] = i2;
                int oldslot = (c4r[i2] >= 0) ? slot4row[i2] : -1;
                c4r[i2] = colidV[jslot];
                slot4row[i2] = jslot;
                if (i2 == cur) break;
                jslot = oldslot;
            }
        }
        costV[lane][snew]      = pfa;
        costV[lane + 64][snew] = pfb;
        __syncthreads();   // publish costV/u_l/c4r/slot4row for next cur
    }

    if (lane == 0 && fail) *failFlag = 1;
    __syncthreads();
    if (!fail) {
        for (int w = lane; w < 2048; w += 64) usedbits[w] = 0u;
        __syncthreads();
        for (int r = lane; r < NGT; r += 64) {
            int p = c4r[r];
            atomicOr(&usedbits[p >> 5], 1u << (p & 31));
            out[r] = p;
            out[1408 + r] = r;
        }
    }
}

// dense fallback: only runs if k_lsa_sparse flagged overflow (should never happen)
__global__ __launch_bounds__(1024) void k_lsa_dense(
    const float* __restrict__ costT, const int* __restrict__ failFlag,
    double* __restrict__ v, double* __restrict__ shortest,
    int* __restrict__ path, int* __restrict__ row4col,
    unsigned char* __restrict__ SC, unsigned* __restrict__ usedbits,
    int* __restrict__ out)
{
#pragma clang fp contract(off)
    if (*failFlag == 0) return;
    __shared__ double u_l[NGT];
    __shared__ int    c4r[NGT];
    __shared__ int    SR[NGT + 1];
    __shared__ int    bi, bsink, nSR;
    __shared__ double bmin;
    __shared__ double wval[16];
    __shared__ int    widx[16];
    int tid = threadIdx.x;

    for (int j = tid; j < NPRED; j += 1024) { v[j] = 0.0; row4col[j] = -1; }
    if (tid < NGT) { u_l[tid] = 0.0; c4r[tid] = -1; }
    __syncthreads();

    for (int cur = 0; cur < NGT; ++cur) {
        for (int j = tid; j < NPRED; j += 1024) {
            shortest[j] = (double)INFINITY; path[j] = -1; SC[j] = 0;
        }
        if (tid == 0) { bi = cur; bsink = -1; bmin = 0.0; SR[0] = cur; nSR = 1; }
        __syncthreads();

        while (true) {
            int irow = bi;
            double mv = bmin;
            double ui = u_l[irow];
            const float* crow = costT + (size_t)irow * NPRED;
            double bestv = (double)INFINITY;
            int    bestj = SENT_I;
            for (int j = tid; j < NPRED; j += 1024) {
                if (!SC[j]) {
                    double s = shortest[j];
                    double r = ((mv + (double)crow[j]) - ui) - v[j];
                    if (r < s) { s = r; shortest[j] = r; path[j] = irow; }
                    if (s < bestv || (s == bestv && j < bestj)) { bestv = s; bestj = j; }
                }
            }
            for (int off = 32; off; off >>= 1) {
                double ov = __shfl_down(bestv, off, 64);
                int    oj = __shfl_down(bestj, off, 64);
                if (ov < bestv || (ov == bestv && oj < bestj)) { bestv = ov; bestj = oj; }
            }
            if ((tid & 63) == 0) { wval[tid >> 6] = bestv; widx[tid >> 6] = bestj; }
            __syncthreads();
            if (tid == 0) {
                double bv = wval[0]; int bj = widx[0];
                for (int w = 1; w < 16; ++w) {
                    double ov = wval[w]; int oj = widx[w];
                    if (ov < bv || (ov == bv && oj < bj)) { bv = ov; bj = oj; }
                }
                bmin = bv;
                SC[bj] = 1;
                int r = row4col[bj];
                if (r < 0) { bsink = bj; }
                else       { SR[nSR++] = r; bi = r; }
            }
            __syncthreads();
            if (bsink >= 0) break;
        }

        double mv = bmin;
        for (int j = tid; j < NPRED; j += 1024)
            if (SC[j]) v[j] -= (mv - shortest[j]);
        if (tid == 0) {
            u_l[cur] += mv;
            for (int k = 1; k < nSR; ++k) {
                int i2 = SR[k];
                u_l[i2] += mv - shortest[c4r[i2]];
            }
            int j = bsink;
            while (true) {
                int i2 = path[j];
                row4col[j] = i2;
                int nj = c4r[i2];
                c4r[i2] = j;
                j = nj;
                if (i2 == cur) break;
            }
        }
        __syncthreads();
    }

    for (int w = tid; w < 2048; w += 1024) usedbits[w] = 0u;
    __syncthreads();
    for (int j = tid; j < NPRED; j += 1024)
        if (row4col[j] >= 0) atomicOr(&usedbits[j >> 5], 1u << (j & 31));
    if (tid < NGT) {
        out[tid]        = c4r[tid];
        out[1408 + tid] = tid;
    }
}

// per-gt: histogram-select top >=KMIN by (val desc, idx asc), compact <=KEEP-1,
// bitonic-sort KEEP u64 keys in LDS, write sorted prefix.
__global__ __launch_bounds__(256) void k_prep(
    const int2* __restrict__ cpair, const int* __restrict__ ccnt,
    unsigned long long* __restrict__ scand, int* __restrict__ kcount,
    int* __restrict__ fullflag)
{
    __shared__ int hist[256];
    __shared__ unsigned long long keys[KEEP];
    __shared__ unsigned sh_pref, sh_thresh;
    __shared__ int sh_done, sh_fail, sh_cnt;
    int tid = threadIdx.x;
    int g = blockIdx.x;
    int nc = ccnt[g]; if (nc > CAP) nc = CAP;
    const int2* src = cpair + (size_t)g * CAP;

    unsigned thresh = 0;
    if (nc > KEEP - 1) {
        if (tid == 0) { sh_pref = 0; sh_done = 0; sh_fail = 0; }
        __syncthreads();
        int above = 0;
        for (int byt = 3; byt >= 0; --byt) {
            hist[tid] = 0;
            __syncthreads();
            unsigned pref = sh_pref;
            for (int c = tid; c < nc; c += 256) {
                unsigned u = f2u(__int_as_float(src[c].y));
                if (byt == 3 || (u >> ((byt + 1) * 8)) == (pref >> ((byt + 1) * 8)))
                    atomicAdd(&hist[(u >> (byt * 8)) & 255], 1);
            }
            __syncthreads();
            if (tid == 0) {
                int cum = 0, B = 0, kept = 0, abnew = above;
                for (int b = 255; b >= 0; --b) {
                    if (above + cum + hist[b] >= KMIN) {
                        B = b; kept = above + cum + hist[b]; abnew = above + cum; break;
                    }
                    cum += hist[b];
                }
                if (kept <= KEEP - 1) { sh_thresh = sh_pref | ((unsigned)B << (byt * 8)); sh_done = 1; }
                else {
                    above = abnew;
                    sh_pref = sh_pref | ((unsigned)B << (byt * 8));
                    if (byt == 0) sh_fail = 1;
                }
            }
            __syncthreads();
            if (sh_done || sh_fail) break;
        }
        if (sh_fail) {
            if (tid == 0) { fullflag[g] = 1; kcount[g] = 0; }
            return;
        }
        thresh = sh_thresh;
    }
    if (tid == 0) sh_cnt = 0;
    __syncthreads();
    for (int c = tid; c < nc; c += 256) {
        unsigned u = f2u(__int_as_float(src[c].y));
        if (u >= thresh) {
            int slot = atomicAdd(&sh_cnt, 1);
            keys[slot] = ((unsigned long long)(~u) << 32) | (unsigned)src[c].x;
        }
    }
    __syncthreads();
    int kept = sh_cnt;
    for (int i = tid; i < KEEP; i += 256) if (i >= kept) keys[i] = ~0ull;
    __syncthreads();
    for (int k = 2; k <= KEEP; k <<= 1) {
        for (int j = k >> 1; j > 0; j >>= 1) {
            for (int i = tid; i < KEEP; i += 256) {
                int ixj = i ^ j;
                if (ixj > i) {
                    unsigned long long a = keys[i], b = keys[ixj];
                    bool up = ((i & k) == 0);
                    if ((up && a > b) || (!up && a < b)) { keys[i] = b; keys[ixj] = a; }
                }
            }
            __syncthreads();
        }
    }
    for (int i = tid; i < KEEP; i += 256) scand[(size_t)g * KEEP + i] = keys[i];
    if (tid == 0) { kcount[g] = kept; fullflag[g] = 0; }
}

// sequential dynamic assignment, single wave
__global__ __launch_bounds__(64) void k_dyn2(
    const int* __restrict__ order, const int* __restrict__ kcount,
    const unsigned long long* __restrict__ scand, const int* __restrict__ fullflag,
    const int* __restrict__ ccnt, const int2* __restrict__ cpair,
    const unsigned* __restrict__ usedbits_g, const int* __restrict__ failFlag,
    int* __restrict__ out)
{
    __shared__ unsigned bits[2048];
    int lane = threadIdx.x;
    for (int w = lane; w < 2048; w += 64) bits[w] = usedbits_g[w];
    __syncthreads();
    bool globalFull = (*failFlag != 0);

    for (int k = 0; k < NGT; ++k) {
        int gt = order[k];
        int got = 0;
        if (!globalFull && fullflag[gt] == 0) {
            int kept = kcount[gt];
            int base = 0;
            while (got < 10 && base < kept) {
                int i = base + lane;
                unsigned long long key = (i < kept) ? scand[(size_t)gt * KEEP + i] : ~0ull;
                int p = (int)(unsigned)(key & 0xFFFFFFFFull);
                bool ok = (key != ~0ull) && !((bits[p >> 5] >> (p & 31)) & 1u);
                unsigned long long mask = __ballot(ok);
                int need = 10 - got;
                int pre = __popcll(mask & ((1ull << lane) - 1ull));
                if (ok && pre < need) {
                    out[128 + k * 10 + got + pre] = p;
                    out[1408 + 128 + k * 10 + got + pre] = gt;
                    atomicOr(&bits[p >> 5], 1u << (p & 31));
                }
                int tot = __popcll(mask);
                got += (tot < need) ? tot : need;
                base += 64;
                __syncthreads();
            }
        } else {
            int nc = ccnt[gt]; if (nc > CAP) nc = CAP;
            float lv[10]; int li[10];
#pragma unroll
            for (int q = 0; q < 10; ++q) { lv[q] = -1e30f; li[q] = SENT_I; }
            for (int c = lane; c < nc; c += 64) {
                int2 pr = cpair[(size_t)gt * CAP + c];
                int p = pr.x;
                if ((bits[p >> 5] >> (p & 31)) & 1u) continue;
                float cv = __int_as_float(pr.y); int ci = p;
#pragma unroll
                for (int q = 0; q < 10; ++q) {
                    bool b = (cv > lv[q]) || (cv == lv[q] && ci < li[q]);
                    float tv = b ? lv[q] : cv; int ti = b ? li[q] : ci;
                    if (b) { lv[q] = cv; li[q] = ci; }
                    cv = tv; ci = ti;
                }
            }
#pragma unroll
            for (int q = 0; q < 10; ++q) {
                float mo = lv[0]; int mj = li[0];
#pragma unroll
                for (int off = 1; off < 64; off <<= 1) {
                    float ov = __shfl_xor(mo, off, 64);
                    int oj = __shfl_xor(mj, off, 64);
                    if (ov > mo || (ov == mo && oj < mj)) { mo = ov; mj = oj; }
                }
                bool valid = (mj != SENT_I);
                if (valid && li[0] == mj) {
#pragma unroll
                    for (int t = 0; t < 9; ++t) { lv[t] = lv[t + 1]; li[t] = li[t + 1]; }
                    lv[9] = -1e30f; li[9] = SENT_I;
                }
                if (lane == q) {
                    out[128 + k * 10 + q] = valid ? mj : -1;
                    out[1408 + 128 + k * 10 + q] = valid ? gt : -1;
                    if (valid) atomicOr(&bits[mj >> 5], 1u << (mj & 31));
                }
            }
            got = 10;
            __syncthreads();
        }
        for (int q = got + lane; q < 10; q += 64) {
            out[128 + k * 10 + q] = -1;
            out[1408 + 128 + k * 10 + q] = -1;
        }
        __syncthreads();
    }
}

// ---------- launch ----------

extern "C" void kernel_launch(void* const* d_in, const int* in_sizes, int n_in,
                              void* d_out, int out_size, void* d_ws, size_t ws_size,
                              hipStream_t stream) {
    const float* pc  = (const float*)d_in[0];
    const float* ps  = (const float*)d_in[1];
    const float* cls = (const float*)d_in[2];
    const float* gc  = (const float*)d_in[4];
    const float* gs  = (const float*)d_in[5];
    const int*   lab = (const int*)d_in[6];

    char* ws = (char*)d_ws;
    float*         costT    = (float*)(ws + 0);                  // 33,554,432
    unsigned long long* scand = (unsigned long long*)(ws + 0);   //  2,097,152 (over costT; k_prep runs after LSA)
    int2*          rowlist  = (int2*)(ws + 33554432);            //    135,168 (over v)
    double*        v        = (double*)(ws + 33554432);          //    524,288 (fallback only)
    double*        shortest = (double*)(ws + 34078720);          //    524,288 (fallback only)
    int*           path     = (int*)(ws + 34603008);             //    262,144 (fallback only)
    int*           row4col  = (int*)(ws + 34865152);             //    262,144 (fallback only)
    unsigned char* SC       = (unsigned char*)(ws + 35127296);   //     65,536 (fallback only)
    int*           kcount   = (int*)(ws + 35192832);
    int*           fullflag = (int*)(ws + 35193344);
    int*           ccnt     = (int*)(ws + 35193856);
    unsigned*      cmax     = (unsigned*)(ws + 35194368);
    int*           order    = (int*)(ws + 35194880);
    int*           failFlag = (int*)(ws + 35195392);
    unsigned*      usedbits = (unsigned*)(ws + 35195904);        //      8,192
    int2*          cpair    = (int2*)(ws + 35204096);            // 12,582,912 -> end 47,787,008

    int* out = (int*)d_out;

    hipLaunchKernelGGL(k_gather, dim3(NPRED / 64), dim3(256), 0, stream,
                       cls, lab, costT, ccnt, cmax, failFlag);
    hipLaunchKernelGGL(k_cost, dim3((NPRED / 256) * GSPLIT), dim3(256), 0, stream,
                       pc, ps, gc, gs, costT, ccnt, cmax, cpair);
    hipLaunchKernelGGL(k_toprow, dim3(NGT + 1), dim3(512), 0, stream,
                       costT, rowlist, cmax, order);
    hipLaunchKernelGGL(k_lsa_sparse, dim3(1), dim3(64), 0, stream,
                       costT, rowlist, failFlag, usedbits, out);
    hipLaunchKernelGGL(k_lsa_dense, dim3(1), dim3(1024), 0, stream,
                       costT, failFlag, v, shortest, path, row4col, SC, usedbits, out);
    hipLaunchKernelGGL(k_prep, dim3(NGT), dim3(256), 0, stream,
                       cpair, ccnt, scand, kcount, fullflag);
    hipLaunchKernelGGL(k_dyn2, dim3(1), dim3(64), 0, stream,
                       order, kcount, scand, fullflag, ccnt, cpair, usedbits, failFlag, out);
}